// Round 12
// baseline (505.955 us; speedup 1.0000x reference)
//
#include <hip/hip_runtime.h>
#include <stdint.h>
#include <math.h>

typedef __bf16 bf16;
typedef __bf16 bf16x4 __attribute__((ext_vector_type(4)));
typedef __bf16 bf16x8 __attribute__((ext_vector_type(8)));
typedef short short4v __attribute__((ext_vector_type(4)));
typedef float floatx4 __attribute__((ext_vector_type(4)));

#define MFMA32(a, b, c) __builtin_amdgcn_mfma_f32_16x16x32_bf16((a), (b), (c), 0, 0, 0)

__device__ __forceinline__ floatx4 mfma16(bf16x4 a, bf16x4 b, floatx4 c) {
  return __builtin_amdgcn_mfma_f32_16x16x16bf16_1k(
      __builtin_bit_cast(short4v, a), __builtin_bit_cast(short4v, b), c, 0, 0, 0);
}

__device__ __forceinline__ void gload16(const void* g, void* l) {
  __builtin_amdgcn_global_load_lds(
      (const __attribute__((address_space(1))) void*)g,
      (__attribute__((address_space(3))) void*)l, 16, 0, 0);
}

__device__ __forceinline__ bf16x8 load8(const float* p) {
  float4 lo = *(const float4*)p;
  float4 hi = *(const float4*)(p + 4);
  bf16x8 r;
  r[0] = (bf16)lo.x; r[1] = (bf16)lo.y; r[2] = (bf16)lo.z; r[3] = (bf16)lo.w;
  r[4] = (bf16)hi.x; r[5] = (bf16)hi.y; r[6] = (bf16)hi.z; r[7] = (bf16)hi.w;
  return r;
}

// One launch converting x, Wq, Wo to bf16. grid (2048, 3), 8 elems/thread.
__global__ __launch_bounds__(256) void conv3(const float* __restrict__ a, bf16* __restrict__ ab,
                                             const float* __restrict__ b, bf16* __restrict__ bb,
                                             const float* __restrict__ c, bf16* __restrict__ cb) {
  const int i = blockIdx.x * 256 + threadIdx.x;
  const float* src = blockIdx.y == 0 ? a : (blockIdx.y == 1 ? b : c);
  bf16* dst = blockIdx.y == 0 ? ab : (blockIdx.y == 1 ? bb : cb);
  ((bf16x8*)dst)[i] = load8(src + (size_t)i * 8);
}

// Pack K (f32->bf16) and transpose-pack V: Vf[t][64] -> Vtb[d][2048].
__global__ __launch_bounds__(256) void pack_kv(const float* __restrict__ Kf,
                                               const float* __restrict__ Vf,
                                               bf16* __restrict__ Kb,
                                               bf16* __restrict__ Vtb) {
  int i = blockIdx.x * 256 + threadIdx.x;
  if (i < 2048 * 64) {
    Kb[i] = (bf16)Kf[i];
    const int t = i >> 6, d = i & 63;
    Vtb[(size_t)d * 2048 + t] = (bf16)Vf[i];
  }
}

// C[M,N] = A[M,K] @ B[N,K]^T, bf16 in, dbuf global_load_lds staging.
// R11-verified (XCD remap kept: null but harmless; plain stores — R10's
// split-K atomics regressed).
template <typename TC>
__global__ __launch_bounds__(256) void gemm_bt_a(const bf16* __restrict__ A,
                                                 const bf16* __restrict__ B,
                                                 TC* __restrict__ C,
                                                 int M, int N, int K) {
  __shared__ __align__(16) bf16 As[2][64 * 32];
  __shared__ __align__(16) bf16 Bs[2][128 * 32];
  const int tid = threadIdx.x;
  const int wave = tid >> 6, lane = tid & 63;
  const int quad = lane >> 4, l16 = lane & 15;
  const int wg = blockIdx.y * 16 + blockIdx.x;
  const int wgid = (wg & 7) * 64 + (wg >> 3);
  const int m0 = (wgid >> 4) * 64, n0 = (wgid & 15) * 128;
  const int wm = (wave >> 1) * 32, wn = (wave & 1) * 64;

  floatx4 acc[2][4];
#pragma unroll
  for (int i = 0; i < 2; i++)
#pragma unroll
    for (int j = 0; j < 4; j++) acc[i][j] = (floatx4)0.f;

  const int srow = tid >> 2;
  const int scol = ((tid & 3) ^ ((tid >> 3) & 3)) * 8;
  const bf16* Ap = A + (size_t)(m0 + srow) * K + scol;
  const bf16* Bp = B + (size_t)(n0 + srow) * K + scol;

  auto stage = [&](int k0, int buf) {
    gload16(Ap + k0, (char*)As[buf] + tid * 16);
    gload16(Bp + k0, (char*)Bs[buf] + tid * 16);
    gload16(Bp + (size_t)64 * K + k0, (char*)Bs[buf] + 4096 + tid * 16);
  };
  const int sxg = (l16 >> 1) & 3;
  auto compute = [&](int buf) {
    bf16x8 af[2], bfr[4];
#pragma unroll
    for (int mt = 0; mt < 2; mt++)
      af[mt] = *(const bf16x8*)(&As[buf][(wm + mt * 16 + l16) * 32 + ((quad ^ sxg) * 8)]);
#pragma unroll
    for (int nt = 0; nt < 4; nt++)
      bfr[nt] = *(const bf16x8*)(&Bs[buf][(wn + nt * 16 + l16) * 32 + ((quad ^ sxg) * 8)]);
#pragma unroll
    for (int mt = 0; mt < 2; mt++)
#pragma unroll
      for (int nt = 0; nt < 4; nt++)
        acc[mt][nt] = MFMA32(af[mt], bfr[nt], acc[mt][nt]);
  };

  stage(0, 0);
  for (int k0 = 0; k0 < K; k0 += 64) {
    __syncthreads();
    if (k0 + 32 < K) stage(k0 + 32, 1);
    compute(0);
    __syncthreads();
    if (k0 + 64 < K) stage(k0 + 64, 0);
    compute(1);
  }

#pragma unroll
  for (int mt = 0; mt < 2; mt++) {
#pragma unroll
    for (int nt = 0; nt < 4; nt++) {
      const int col = n0 + wn + nt * 16 + l16;
      const int row = m0 + wm + mt * 16 + quad * 4;
#pragma unroll
      for (int r = 0; r < 4; r++)
        C[(size_t)(row + r) * N + col] = (TC)acc[mt][nt][r];
    }
  }
}

// Fused K+V projection, split-K x8. A = xb (bf16), B = Wk/Wv (f32 -> bf16).
__global__ __launch_bounds__(256) void kv_gemm(const bf16* __restrict__ xb,
                                               const float* __restrict__ Wk,
                                               const float* __restrict__ Wv,
                                               float* __restrict__ Kf,
                                               float* __restrict__ Vf) {
  __shared__ __align__(16) bf16 As[128 * 40];
  __shared__ __align__(16) bf16 Bs[128 * 40];
  const int tid = threadIdx.x;
  const int wave = tid >> 6, lane = tid & 63;
  const int quad = lane >> 4, l16 = lane & 15;
  const int m0 = blockIdx.y * 128;
  const int kbeg = blockIdx.x * 256, kend = kbeg + 256;
  const int wm = (wave >> 1) * 64, wn = (wave & 1) * 64;

  floatx4 acc[4][4];
#pragma unroll
  for (int i = 0; i < 4; i++)
#pragma unroll
    for (int j = 0; j < 4; j++) acc[i][j] = (floatx4)0.f;

  const int sr = tid >> 2, sc = (tid & 3) * 8;

  for (int k0 = kbeg; k0 < kend; k0 += 32) {
    __syncthreads();
#pragma unroll
    for (int rr = 0; rr < 2; rr++) {
      const int row = sr + rr * 64;
      *(bf16x8*)(&As[row * 40 + sc]) =
          *(const bf16x8*)(&xb[(size_t)(m0 + row) * 2048 + k0 + sc]);
      const float* bsrc = (row < 64) ? &Wk[(size_t)row * 2048 + k0 + sc]
                                     : &Wv[(size_t)(row - 64) * 2048 + k0 + sc];
      *(bf16x8*)(&Bs[row * 40 + sc]) = load8(bsrc);
    }
    __syncthreads();

    bf16x8 af[4], bfr[4];
#pragma unroll
    for (int mt = 0; mt < 4; mt++)
      af[mt] = *(const bf16x8*)(&As[(wm + mt * 16 + l16) * 40 + quad * 8]);
#pragma unroll
    for (int nt = 0; nt < 4; nt++)
      bfr[nt] = *(const bf16x8*)(&Bs[(wn + nt * 16 + l16) * 40 + quad * 8]);
#pragma unroll
    for (int mt = 0; mt < 4; mt++)
#pragma unroll
      for (int nt = 0; nt < 4; nt++)
        acc[mt][nt] = MFMA32(af[mt], bfr[nt], acc[mt][nt]);
  }

#pragma unroll
  for (int mt = 0; mt < 4; mt++) {
#pragma unroll
    for (int nt = 0; nt < 4; nt++) {
      const int col = wn + nt * 16 + l16;
      const int row = m0 + wm + mt * 16 + quad * 4;
      float* dst = (col < 64) ? &Kf[(size_t)row * 64 + col]
                              : &Vf[(size_t)row * 64 + (col - 64)];
#pragma unroll
      for (int r = 0; r < 4; r++) atomicAdd(dst + (size_t)r * 64, acc[mt][nt][r]);
    }
  }
}

#define WTHR 30.f

// Rank the 1024 (pair, half) attention blocks by load (counting sort on
// loads 0..16 via LDS), write table[rank] = (half<<9)|pair, and zero the
// 512 per-pair combine flags (workspace is poisoned every iteration).
__global__ __launch_bounds__(1024) void mktable(uint32_t* __restrict__ tbl,
                                                uint32_t* __restrict__ flags) {
  __shared__ int bins[17], base[17];
  const int i = threadIdx.x;
  if (i < 512) flags[i] = 0;
  const int p = i & 511, hf = i >> 9;
  const int h = p & 31, t = p >> 5;
  const float slope2 = exp2f(-0.25f * (float)(h + 1)) * 1.44269504f;
  const int lo_key = t * 128 - (int)(WTHR / slope2);
  const int lo_t = (lo_key <= 0) ? 0 : (lo_key >> 6);
  const int m = 2 * t + 2 - lo_t;                 // tiles for this pair (>=2)
  const int load = hf ? (m >> 1) : ((m + 1) >> 1);
  if (i < 17) bins[i] = 0;
  __syncthreads();
  atomicAdd(&bins[load], 1);
  __syncthreads();
  if (i == 0) {  // descending prefix: base[v] = # blocks with load > v
    int s = 0;
    for (int v = 16; v >= 0; --v) { base[v] = s; s += bins[v]; }
  }
  __syncthreads();
  if (i < 17) bins[i] = 0;
  __syncthreads();
  const int off = atomicAdd(&bins[load], 1);
  const int rank = base[load] + off;
  tbl[rank] = ((uint32_t)hf << 9) | (uint32_t)p;
}

// Flash attention, deterministic 2-way split per (h, q-tile) — R7-proven
// body + R12 additions: (a) s_setprio(1) around MFMA clusters (T5, m191:
// +4-7% on independent-block attn); (b) fused finisher-combine replacing
// norm_o: both halves publish partials; the block whose device-scope
// atomicAdd(flag) returns 1 (ticket) reads the partner slice (release:
// __syncthreads drains stores, tid0 __threadfence publishes; acquire:
// __threadfence before reads), adds its in-register partial, normalizes,
// writes bf16 AO. Exactly one AO write per (qi,h); no spinning.
__global__ __launch_bounds__(512) void attn_kernel(const bf16* __restrict__ Q,
                                                   const bf16* __restrict__ Kb,
                                                   const bf16* __restrict__ Vtb,
                                                   float* __restrict__ OpA,
                                                   float* __restrict__ OpB,
                                                   float* __restrict__ lpart,
                                                   uint32_t* __restrict__ flags,
                                                   bf16* __restrict__ AO,
                                                   const uint32_t* __restrict__ tbl) {
  __shared__ __align__(16) bf16 Ks[2][64 * 64];  // [buf][key][d] swizzled
  __shared__ __align__(16) bf16 Vt[2][64 * 64];  // [buf][d][key] swizzled
  __shared__ int sdone;

  const int u = blockIdx.x & 255, sfold = blockIdx.x >> 8;
  const int r = (sfold == 0) ? u : (sfold == 1) ? (511 - u)
                : (sfold == 2) ? (512 + u) : (1023 - u);
  const uint32_t e = tbl[r];
  const int p = e & 511, hf = (int)(e >> 9);
  const int h = p & 31, t = p >> 5;

  const float slope2 = exp2f(-0.25f * (float)(h + 1)) * 1.44269504f;
  const int lo_key = t * 128 - (int)(WTHR / slope2);
  const int lo_t = (lo_key <= 0) ? 0 : (lo_key >> 6);
  const int m = 2 * t + 2 - lo_t;        // >= 2
  const int c0 = (m + 1) >> 1;
  const int kbeg = hf ? (lo_t + c0) : lo_t;
  const int cnt = hf ? (m >> 1) : c0;    // >= 1 always

  const int tid = threadIdx.x;
  const int wave = tid >> 6;  // 0..7 -> q-rows wave*16..+15
  const int lane = tid & 63;
  const int quad = lane >> 4, l16 = lane & 15;
  const float scale2 = 0.125f * 1.44269504f;
  const bf16x4 ones = {(bf16)1.f, (bf16)1.f, (bf16)1.f, (bf16)1.f};

  float cq[4];
#pragma unroll
  for (int rr = 0; rr < 4; rr++) cq[rr] = slope2 * (float)(quad * 4 + rr);
  const float s16 = slope2 * 16.f;

  const int qi = t * 128 + wave * 16 + l16;
  const int qw0 = t * 128 + wave * 16;
  bf16x8 qf[2];
#pragma unroll
  for (int kk = 0; kk < 2; kk++)
    qf[kk] = *(const bf16x8*)(&Q[(size_t)qi * 2048 + h * 64 + kk * 32 + quad * 8]);

  floatx4 oacc[4];
#pragma unroll
  for (int dt = 0; dt < 4; dt++) oacc[dt] = (floatx4)0.f;
  floatx4 lacc = (floatx4)0.f;

  // staging: 512 threads stage 64x64 K and V tiles (one bf16x8 each)
  const int r0 = tid >> 3, sl = tid & 7;     // row 0..63, 16B slot 0..7
  const int wsw = ((sl ^ (r0 & 7)) << 3);    // XOR-swizzled elem offset
  const int sx = l16 & 7;                    // read-side swizzle bits

  const int kn = kbeg * 64;
  bf16x8 kreg = *(const bf16x8*)(&Kb[(size_t)(kn + r0) * 64 + sl * 8]);
  bf16x8 vreg = *(const bf16x8*)(&Vtb[(size_t)r0 * 2048 + kn + sl * 8]);

  for (int i = 0; i < cnt; i++) {
    const int kt = kbeg + i;
    const int buf = i & 1;
    *(bf16x8*)(&Ks[buf][r0 * 64 + wsw]) = kreg;
    *(bf16x8*)(&Vt[buf][r0 * 64 + wsw]) = vreg;
    __syncthreads();  // tile kt visible
    if (i + 1 < cnt) {  // prefetch next tile (kt+1 <= 31 by construction)
      const int kn2 = (kt + 1) * 64;
      kreg = *(const bf16x8*)(&Kb[(size_t)(kn2 + r0) * 64 + sl * 8]);
      vreg = *(const bf16x8*)(&Vtb[(size_t)r0 * 2048 + kn2 + sl * 8]);
    }
    const int k0 = kt * 64;
    if (k0 > qw0 + 15) continue;                               // causal skip
    if ((float)(qw0 - k0 - 63) * slope2 > WTHR) continue;      // ALiBi window

    const bf16* ks = Ks[buf];
    const bf16* vs = Vt[buf];

    // S^T[key][q] = K . Q^T
    floatx4 s[4];
#pragma unroll
    for (int mt = 0; mt < 4; mt++) s[mt] = (floatx4)0.f;
    __builtin_amdgcn_s_setprio(1);
#pragma unroll
    for (int kk = 0; kk < 2; kk++) {
#pragma unroll
      for (int mt = 0; mt < 4; mt++) {
        bf16x8 kf = *(const bf16x8*)(
            &ks[(mt * 16 + l16) * 64 + (((kk * 4 + quad) ^ sx) << 3)]);
        s[mt] = MFMA32(kf, qf[kk], s[mt]);
      }
    }
    __builtin_amdgcn_s_setprio(0);

    // p = exp2(s*scale2 + slope2*(j-i)); scores bounded -> no running max
    const float base0 = slope2 * (float)(k0 - qi);
    bf16x4 pb[4];
    if (k0 + 63 <= qw0) {  // interior for the whole wave: no mask
      float b = base0;
#pragma unroll
      for (int mt = 0; mt < 4; mt++) {
        bf16x4 tb;
#pragma unroll
        for (int rr = 0; rr < 4; rr++)
          tb[rr] = (bf16)exp2f(__builtin_fmaf(s[mt][rr], scale2, b + cq[rr]));
        pb[mt] = tb;
        b += s16;
      }
    } else {  // diagonal tile: per-lane causal mask
      const int qloc = qi - k0;
      float b = base0;
#pragma unroll
      for (int mt = 0; mt < 4; mt++) {
        bf16x4 tb;
#pragma unroll
        for (int rr = 0; rr < 4; rr++) {
          const int moff = mt * 16 + quad * 4 + rr;
          const float pv = exp2f(__builtin_fmaf(s[mt][rr], scale2, b + cq[rr]));
          tb[rr] = (moff <= qloc) ? (bf16)pv : (bf16)0.f;
        }
        pb[mt] = tb;
        b += s16;
      }
    }

    // O^T[d][q] += V^T . P^T ; l += 1 . P^T (matrix-pipe row-sum)
    __builtin_amdgcn_s_setprio(1);
#pragma unroll
    for (int mt = 0; mt < 4; mt++) {
      lacc = mfma16(ones, pb[mt], lacc);
#pragma unroll
      for (int dt = 0; dt < 4; dt++) {
        const int slot = 2 * mt + (quad >> 1);
        const bf16x4 va = *(const bf16x4*)(
            &vs[(dt * 16 + l16) * 64 + ((slot ^ sx) << 3) + (quad & 1) * 4]);
        oacc[dt] = mfma16(va, pb[mt], oacc[dt]);
      }
    }
    __builtin_amdgcn_s_setprio(0);
  }

  // publish partial (plain f32 stores; each (hf,qi,h) slot written once)
  float* op = (hf ? OpB : OpA) + (size_t)qi * 2048 + h * 64;
#pragma unroll
  for (int dt = 0; dt < 4; dt++)
#pragma unroll
    for (int rr = 0; rr < 4; rr++)
      op[dt * 16 + quad * 4 + rr] = oacc[dt][rr];
  if (quad == 0) lpart[(size_t)hf * 65536 + (size_t)qi * 32 + h] = lacc[0];

  // ticket: second finisher combines + normalizes (replaces norm_o)
  __syncthreads();  // all stores drained (barrier implies vmcnt(0))
  if (tid == 0) {
    __threadfence();  // release: partials visible device-wide
    sdone = (int)atomicAdd(&flags[p], 1u);
  }
  __syncthreads();
  if (sdone == 1) {  // partner already published: we combine
    __threadfence();  // acquire: invalidate stale cache lines
    const float* pp = (hf ? OpA : OpB) + (size_t)qi * 2048 + h * 64;
    const float pl = lpart[(size_t)(hf ^ 1) * 65536 + (size_t)qi * 32 + h];
    const float linv = 1.f / (lacc[0] + pl);
#pragma unroll
    for (int dt = 0; dt < 4; dt++) {
      bf16x4 ob;
#pragma unroll
      for (int rr = 0; rr < 4; rr++)
        ob[rr] = (bf16)((oacc[dt][rr] + pp[dt * 16 + quad * 4 + rr]) * linv);
      *(bf16x4*)(&AO[(size_t)qi * 2048 + h * 64 + dt * 16 + quad * 4]) = ob;
    }
  }
}

extern "C" void kernel_launch(void* const* d_in, const int* in_sizes, int n_in,
                              void* d_out, int out_size, void* d_ws,
                              size_t ws_size, hipStream_t stream) {
  (void)in_sizes; (void)n_in; (void)out_size; (void)ws_size;
  const float* x = (const float*)d_in[0];
  const float* Wq = (const float*)d_in[1];
  const float* Wk = (const float*)d_in[2];
  const float* Wv = (const float*)d_in[3];
  const float* Wo = (const float*)d_in[4];
  float* out = (float*)d_out;

  const size_t NE = (size_t)2048 * 2048;
  bf16* xb = (bf16*)d_ws;              // 8 MB (reused as OpA lo half)
  bf16* Wqb = xb + NE;                 // 8 MB (reused as OpA hi half)
  bf16* Wob = Wqb + NE;                // 8 MB
  bf16* Qb = Wob + NE;                 // 8 MB (reused as AO after attn)
  float* Kf = (float*)(Qb + NE);       // 512 KB (reused as lpart, both halves)
  float* Vf = Kf + 2048 * 64;          // 512 KB (reused as table + flags)
  bf16* Kb = (bf16*)(Vf + 2048 * 64);  // 256 KB
  bf16* Vtb = Kb + 2048 * 64;          // 256 KB  (end of ws usage: ~33.5 MB)
  float* OpA = (float*)d_ws;           // 16 MB f32, over xb+Wqb (dead by attn)
  float* OpB = out;                    // 16 MB f32 scratch (out written last)
  float* lpart = Kf;                   // 512 KB f32 (l0 + l1), over Kf
  uint32_t* tbl = (uint32_t*)Vf;       // 4 KB, over Vf (dead after pack_kv)
  uint32_t* flags = tbl + 1024;        // 2 KB combine flags (zeroed in mktable)
  bf16* AO = Qb;                       // finisher output (Q dead per-pair)

  (void)hipMemsetAsync(Kf, 0, 2 * 2048 * 64 * sizeof(float), stream);
  conv3<<<dim3(2048, 3), 256, 0, stream>>>(x, xb, Wq, Wqb, Wo, Wob);
  gemm_bt_a<bf16><<<dim3(16, 32), 256, 0, stream>>>(xb, Wqb, Qb, 2048, 2048, 2048);
  kv_gemm<<<dim3(8, 16), 256, 0, stream>>>(xb, Wk, Wv, Kf, Vf);
  pack_kv<<<512, 256, 0, stream>>>(Kf, Vf, Kb, Vtb);
  mktable<<<1, 1024, 0, stream>>>(tbl, flags);
  attn_kernel<<<1024, 512, 0, stream>>>(Qb, Kb, Vtb, OpA, OpB, lpart, flags, AO, tbl);
  gemm_bt_a<float><<<dim3(16, 32), 256, 0, stream>>>(AO, Wob, out, 2048, 2048, 2048);
}

// Round 13
// 237.096 us; speedup vs baseline: 2.1340x; 2.1340x over previous
//
#include <hip/hip_runtime.h>
#include <stdint.h>
#include <math.h>

typedef __bf16 bf16;
typedef __bf16 bf16x4 __attribute__((ext_vector_type(4)));
typedef __bf16 bf16x8 __attribute__((ext_vector_type(8)));
typedef short short4v __attribute__((ext_vector_type(4)));
typedef float floatx4 __attribute__((ext_vector_type(4)));

#define MFMA32(a, b, c) __builtin_amdgcn_mfma_f32_16x16x32_bf16((a), (b), (c), 0, 0, 0)

__device__ __forceinline__ floatx4 mfma16(bf16x4 a, bf16x4 b, floatx4 c) {
  return __builtin_amdgcn_mfma_f32_16x16x16bf16_1k(
      __builtin_bit_cast(short4v, a), __builtin_bit_cast(short4v, b), c, 0, 0, 0);
}

__device__ __forceinline__ void gload16(const void* g, void* l) {
  __builtin_amdgcn_global_load_lds(
      (const __attribute__((address_space(1))) void*)g,
      (__attribute__((address_space(3))) void*)l, 16, 0, 0);
}

__device__ __forceinline__ bf16x8 load8(const float* p) {
  float4 lo = *(const float4*)p;
  float4 hi = *(const float4*)(p + 4);
  bf16x8 r;
  r[0] = (bf16)lo.x; r[1] = (bf16)lo.y; r[2] = (bf16)lo.z; r[3] = (bf16)lo.w;
  r[4] = (bf16)hi.x; r[5] = (bf16)hi.y; r[6] = (bf16)hi.z; r[7] = (bf16)hi.w;
  return r;
}

// One launch converting x, Wq, Wo to bf16. grid (2048, 3), 8 elems/thread.
__global__ __launch_bounds__(256) void conv3(const float* __restrict__ a, bf16* __restrict__ ab,
                                             const float* __restrict__ b, bf16* __restrict__ bb,
                                             const float* __restrict__ c, bf16* __restrict__ cb) {
  const int i = blockIdx.x * 256 + threadIdx.x;
  const float* src = blockIdx.y == 0 ? a : (blockIdx.y == 1 ? b : c);
  bf16* dst = blockIdx.y == 0 ? ab : (blockIdx.y == 1 ? bb : cb);
  ((bf16x8*)dst)[i] = load8(src + (size_t)i * 8);
}

// Pack K (f32->bf16) and transpose-pack V: Vf[t][64] -> Vtb[d][2048].
__global__ __launch_bounds__(256) void pack_kv(const float* __restrict__ Kf,
                                               const float* __restrict__ Vf,
                                               bf16* __restrict__ Kb,
                                               bf16* __restrict__ Vtb) {
  int i = blockIdx.x * 256 + threadIdx.x;
  if (i < 2048 * 64) {
    Kb[i] = (bf16)Kf[i];
    const int t = i >> 6, d = i & 63;
    Vtb[(size_t)d * 2048 + t] = (bf16)Vf[i];
  }
}

// C[M,N] = A[M,K] @ B[N,K]^T, bf16 in, dbuf global_load_lds staging.
// R11-verified (XCD remap: null but harmless; plain stores).
template <typename TC>
__global__ __launch_bounds__(256) void gemm_bt_a(const bf16* __restrict__ A,
                                                 const bf16* __restrict__ B,
                                                 TC* __restrict__ C,
                                                 int M, int N, int K) {
  __shared__ __align__(16) bf16 As[2][64 * 32];
  __shared__ __align__(16) bf16 Bs[2][128 * 32];
  const int tid = threadIdx.x;
  const int wave = tid >> 6, lane = tid & 63;
  const int quad = lane >> 4, l16 = lane & 15;
  const int wg = blockIdx.y * 16 + blockIdx.x;
  const int wgid = (wg & 7) * 64 + (wg >> 3);
  const int m0 = (wgid >> 4) * 64, n0 = (wgid & 15) * 128;
  const int wm = (wave >> 1) * 32, wn = (wave & 1) * 64;

  floatx4 acc[2][4];
#pragma unroll
  for (int i = 0; i < 2; i++)
#pragma unroll
    for (int j = 0; j < 4; j++) acc[i][j] = (floatx4)0.f;

  const int srow = tid >> 2;
  const int scol = ((tid & 3) ^ ((tid >> 3) & 3)) * 8;
  const bf16* Ap = A + (size_t)(m0 + srow) * K + scol;
  const bf16* Bp = B + (size_t)(n0 + srow) * K + scol;

  auto stage = [&](int k0, int buf) {
    gload16(Ap + k0, (char*)As[buf] + tid * 16);
    gload16(Bp + k0, (char*)Bs[buf] + tid * 16);
    gload16(Bp + (size_t)64 * K + k0, (char*)Bs[buf] + 4096 + tid * 16);
  };
  const int sxg = (l16 >> 1) & 3;
  auto compute = [&](int buf) {
    bf16x8 af[2], bfr[4];
#pragma unroll
    for (int mt = 0; mt < 2; mt++)
      af[mt] = *(const bf16x8*)(&As[buf][(wm + mt * 16 + l16) * 32 + ((quad ^ sxg) * 8)]);
#pragma unroll
    for (int nt = 0; nt < 4; nt++)
      bfr[nt] = *(const bf16x8*)(&Bs[buf][(wn + nt * 16 + l16) * 32 + ((quad ^ sxg) * 8)]);
#pragma unroll
    for (int mt = 0; mt < 2; mt++)
#pragma unroll
      for (int nt = 0; nt < 4; nt++)
        acc[mt][nt] = MFMA32(af[mt], bfr[nt], acc[mt][nt]);
  };

  stage(0, 0);
  for (int k0 = 0; k0 < K; k0 += 64) {
    __syncthreads();
    if (k0 + 32 < K) stage(k0 + 32, 1);
    compute(0);
    __syncthreads();
    if (k0 + 64 < K) stage(k0 + 64, 0);
    compute(1);
  }

#pragma unroll
  for (int mt = 0; mt < 2; mt++) {
#pragma unroll
    for (int nt = 0; nt < 4; nt++) {
      const int col = n0 + wn + nt * 16 + l16;
      const int row = m0 + wm + mt * 16 + quad * 4;
#pragma unroll
      for (int r = 0; r < 4; r++)
        C[(size_t)(row + r) * N + col] = (TC)acc[mt][nt][r];
    }
  }
}

// Fused K+V projection, split-K x8. A = xb (bf16), B = Wk/Wv (f32 -> bf16).
__global__ __launch_bounds__(256) void kv_gemm(const bf16* __restrict__ xb,
                                               const float* __restrict__ Wk,
                                               const float* __restrict__ Wv,
                                               float* __restrict__ Kf,
                                               float* __restrict__ Vf) {
  __shared__ __align__(16) bf16 As[128 * 40];
  __shared__ __align__(16) bf16 Bs[128 * 40];
  const int tid = threadIdx.x;
  const int wave = tid >> 6, lane = tid & 63;
  const int quad = lane >> 4, l16 = lane & 15;
  const int m0 = blockIdx.y * 128;
  const int kbeg = blockIdx.x * 256, kend = kbeg + 256;
  const int wm = (wave >> 1) * 64, wn = (wave & 1) * 64;

  floatx4 acc[4][4];
#pragma unroll
  for (int i = 0; i < 4; i++)
#pragma unroll
    for (int j = 0; j < 4; j++) acc[i][j] = (floatx4)0.f;

  const int sr = tid >> 2, sc = (tid & 3) * 8;

  for (int k0 = kbeg; k0 < kend; k0 += 32) {
    __syncthreads();
#pragma unroll
    for (int rr = 0; rr < 2; rr++) {
      const int row = sr + rr * 64;
      *(bf16x8*)(&As[row * 40 + sc]) =
          *(const bf16x8*)(&xb[(size_t)(m0 + row) * 2048 + k0 + sc]);
      const float* bsrc = (row < 64) ? &Wk[(size_t)row * 2048 + k0 + sc]
                                     : &Wv[(size_t)(row - 64) * 2048 + k0 + sc];
      *(bf16x8*)(&Bs[row * 40 + sc]) = load8(bsrc);
    }
    __syncthreads();

    bf16x8 af[4], bfr[4];
#pragma unroll
    for (int mt = 0; mt < 4; mt++)
      af[mt] = *(const bf16x8*)(&As[(wm + mt * 16 + l16) * 40 + quad * 8]);
#pragma unroll
    for (int nt = 0; nt < 4; nt++)
      bfr[nt] = *(const bf16x8*)(&Bs[(wn + nt * 16 + l16) * 40 + quad * 8]);
#pragma unroll
    for (int mt = 0; mt < 4; mt++)
#pragma unroll
      for (int nt = 0; nt < 4; nt++)
        acc[mt][nt] = MFMA32(af[mt], bfr[nt], acc[mt][nt]);
  }

#pragma unroll
  for (int mt = 0; mt < 4; mt++) {
#pragma unroll
    for (int nt = 0; nt < 4; nt++) {
      const int col = wn + nt * 16 + l16;
      const int row = m0 + wm + mt * 16 + quad * 4;
      float* dst = (col < 64) ? &Kf[(size_t)row * 64 + col]
                              : &Vf[(size_t)row * 64 + (col - 64)];
#pragma unroll
      for (int r = 0; r < 4; r++) atomicAdd(dst + (size_t)r * 64, acc[mt][nt][r]);
    }
  }
}

#define WTHR 30.f

// Rank the 1024 (pair, half) attention blocks by load (counting sort on
// loads 0..16 via LDS) and write table[rank] = (half<<9)|pair. R7-proven.
__global__ __launch_bounds__(1024) void mktable(uint32_t* __restrict__ tbl) {
  __shared__ int bins[17], base[17];
  const int i = threadIdx.x;
  const int p = i & 511, hf = i >> 9;
  const int h = p & 31, t = p >> 5;
  const float slope2 = exp2f(-0.25f * (float)(h + 1)) * 1.44269504f;
  const int lo_key = t * 128 - (int)(WTHR / slope2);
  const int lo_t = (lo_key <= 0) ? 0 : (lo_key >> 6);
  const int m = 2 * t + 2 - lo_t;                 // tiles for this pair (>=2)
  const int load = hf ? (m >> 1) : ((m + 1) >> 1);
  if (i < 17) bins[i] = 0;
  __syncthreads();
  atomicAdd(&bins[load], 1);
  __syncthreads();
  if (i == 0) {  // descending prefix: base[v] = # blocks with load > v
    int s = 0;
    for (int v = 16; v >= 0; --v) { base[v] = s; s += bins[v]; }
  }
  __syncthreads();
  if (i < 17) bins[i] = 0;
  __syncthreads();
  const int off = atomicAdd(&bins[load], 1);
  const int rank = base[load] + off;
  tbl[rank] = ((uint32_t)hf << 9) | (uint32_t)p;
}

// Flash attention, deterministic 2-way split per (h, q-tile) — R7-proven
// structure + T5 s_setprio around MFMA clusters (single-variable change vs
// R11; m191: +4-7% in exactly this independent-block regime). R12's fused
// finisher REVERTED: per-block __threadfence = L2 writeback storm on
// non-coherent XCD L2s (324us attn). norm_o restored.
__global__ __launch_bounds__(512) void attn_kernel(const bf16* __restrict__ Q,
                                                   const bf16* __restrict__ Kb,
                                                   const bf16* __restrict__ Vtb,
                                                   float* __restrict__ OpA,
                                                   float* __restrict__ OpB,
                                                   float* __restrict__ lpart,
                                                   const uint32_t* __restrict__ tbl) {
  __shared__ __align__(16) bf16 Ks[2][64 * 64];  // [buf][key][d] swizzled
  __shared__ __align__(16) bf16 Vt[2][64 * 64];  // [buf][d][key] swizzled

  const int u = blockIdx.x & 255, sfold = blockIdx.x >> 8;
  const int r = (sfold == 0) ? u : (sfold == 1) ? (511 - u)
                : (sfold == 2) ? (512 + u) : (1023 - u);
  const uint32_t e = tbl[r];
  const int p = e & 511, hf = (int)(e >> 9);
  const int h = p & 31, t = p >> 5;

  const float slope2 = exp2f(-0.25f * (float)(h + 1)) * 1.44269504f;
  const int lo_key = t * 128 - (int)(WTHR / slope2);
  const int lo_t = (lo_key <= 0) ? 0 : (lo_key >> 6);
  const int m = 2 * t + 2 - lo_t;        // >= 2
  const int c0 = (m + 1) >> 1;
  const int kbeg = hf ? (lo_t + c0) : lo_t;
  const int cnt = hf ? (m >> 1) : c0;    // >= 1 always

  const int tid = threadIdx.x;
  const int wave = tid >> 6;  // 0..7 -> q-rows wave*16..+15
  const int lane = tid & 63;
  const int quad = lane >> 4, l16 = lane & 15;
  const float scale2 = 0.125f * 1.44269504f;
  const bf16x4 ones = {(bf16)1.f, (bf16)1.f, (bf16)1.f, (bf16)1.f};

  float cq[4];
#pragma unroll
  for (int rr = 0; rr < 4; rr++) cq[rr] = slope2 * (float)(quad * 4 + rr);
  const float s16 = slope2 * 16.f;

  const int qi = t * 128 + wave * 16 + l16;
  const int qw0 = t * 128 + wave * 16;
  bf16x8 qf[2];
#pragma unroll
  for (int kk = 0; kk < 2; kk++)
    qf[kk] = *(const bf16x8*)(&Q[(size_t)qi * 2048 + h * 64 + kk * 32 + quad * 8]);

  floatx4 oacc[4];
#pragma unroll
  for (int dt = 0; dt < 4; dt++) oacc[dt] = (floatx4)0.f;
  floatx4 lacc = (floatx4)0.f;

  // staging: 512 threads stage 64x64 K and V tiles (one bf16x8 each)
  const int r0 = tid >> 3, sl = tid & 7;     // row 0..63, 16B slot 0..7
  const int wsw = ((sl ^ (r0 & 7)) << 3);    // XOR-swizzled elem offset
  const int sx = l16 & 7;                    // read-side swizzle bits

  const int kn = kbeg * 64;
  bf16x8 kreg = *(const bf16x8*)(&Kb[(size_t)(kn + r0) * 64 + sl * 8]);
  bf16x8 vreg = *(const bf16x8*)(&Vtb[(size_t)r0 * 2048 + kn + sl * 8]);

  for (int i = 0; i < cnt; i++) {
    const int kt = kbeg + i;
    const int buf = i & 1;
    *(bf16x8*)(&Ks[buf][r0 * 64 + wsw]) = kreg;
    *(bf16x8*)(&Vt[buf][r0 * 64 + wsw]) = vreg;
    __syncthreads();  // tile kt visible
    if (i + 1 < cnt) {  // prefetch next tile (kt+1 <= 31 by construction)
      const int kn2 = (kt + 1) * 64;
      kreg = *(const bf16x8*)(&Kb[(size_t)(kn2 + r0) * 64 + sl * 8]);
      vreg = *(const bf16x8*)(&Vtb[(size_t)r0 * 2048 + kn2 + sl * 8]);
    }
    const int k0 = kt * 64;
    if (k0 > qw0 + 15) continue;                               // causal skip
    if ((float)(qw0 - k0 - 63) * slope2 > WTHR) continue;      // ALiBi window

    const bf16* ks = Ks[buf];
    const bf16* vs = Vt[buf];

    // S^T[key][q] = K . Q^T
    floatx4 s[4];
#pragma unroll
    for (int mt = 0; mt < 4; mt++) s[mt] = (floatx4)0.f;
    __builtin_amdgcn_s_setprio(1);
#pragma unroll
    for (int kk = 0; kk < 2; kk++) {
#pragma unroll
      for (int mt = 0; mt < 4; mt++) {
        bf16x8 kf = *(const bf16x8*)(
            &ks[(mt * 16 + l16) * 64 + (((kk * 4 + quad) ^ sx) << 3)]);
        s[mt] = MFMA32(kf, qf[kk], s[mt]);
      }
    }
    __builtin_amdgcn_s_setprio(0);

    // p = exp2(s*scale2 + slope2*(j-i)); scores bounded -> no running max
    const float base0 = slope2 * (float)(k0 - qi);
    bf16x4 pb[4];
    if (k0 + 63 <= qw0) {  // interior for the whole wave: no mask
      float b = base0;
#pragma unroll
      for (int mt = 0; mt < 4; mt++) {
        bf16x4 tb;
#pragma unroll
        for (int rr = 0; rr < 4; rr++)
          tb[rr] = (bf16)exp2f(__builtin_fmaf(s[mt][rr], scale2, b + cq[rr]));
        pb[mt] = tb;
        b += s16;
      }
    } else {  // diagonal tile: per-lane causal mask
      const int qloc = qi - k0;
      float b = base0;
#pragma unroll
      for (int mt = 0; mt < 4; mt++) {
        bf16x4 tb;
#pragma unroll
        for (int rr = 0; rr < 4; rr++) {
          const int moff = mt * 16 + quad * 4 + rr;
          const float pv = exp2f(__builtin_fmaf(s[mt][rr], scale2, b + cq[rr]));
          tb[rr] = (moff <= qloc) ? (bf16)pv : (bf16)0.f;
        }
        pb[mt] = tb;
        b += s16;
      }
    }

    // O^T[d][q] += V^T . P^T ; l += 1 . P^T (matrix-pipe row-sum)
    __builtin_amdgcn_s_setprio(1);
#pragma unroll
    for (int mt = 0; mt < 4; mt++) {
      lacc = mfma16(ones, pb[mt], lacc);
#pragma unroll
      for (int dt = 0; dt < 4; dt++) {
        const int slot = 2 * mt + (quad >> 1);
        const bf16x4 va = *(const bf16x4*)(
            &vs[(dt * 16 + l16) * 64 + ((slot ^ sx) << 3) + (quad & 1) * 4]);
        oacc[dt] = mfma16(va, pb[mt], oacc[dt]);
      }
    }
    __builtin_amdgcn_s_setprio(0);
  }

  // flush partial (plain f32 stores; each slot written exactly once)
  float* op = (hf ? OpB : OpA) + (size_t)qi * 2048 + h * 64;
#pragma unroll
  for (int dt = 0; dt < 4; dt++)
#pragma unroll
    for (int rr = 0; rr < 4; rr++)
      op[dt * 16 + quad * 4 + rr] = oacc[dt][rr];
  if (quad == 0) lpart[(size_t)hf * 65536 + (size_t)qi * 32 + h] = lacc[0];
}

// AO[qi][e] = (P0+P1)[qi][e] / (l0+l1)[qi][e>>6], bf16. 2048 blocks x 256.
__global__ __launch_bounds__(256) void norm_o(const float* __restrict__ P0,
                                              const float* __restrict__ P1,
                                              const float* __restrict__ L,
                                              bf16* __restrict__ AO) {
  const int idx = blockIdx.x * 256 + threadIdx.x;
  const int qi = idx >> 8;
  const int cs = (idx & 255) << 3;
  const int h = cs >> 6;
  const float l = L[(size_t)qi * 32 + h] + L[65536 + (size_t)qi * 32 + h];
  const float linv = 1.f / l;
  const float4 a0 = *(const float4*)(P0 + (size_t)qi * 2048 + cs);
  const float4 a1 = *(const float4*)(P0 + (size_t)qi * 2048 + cs + 4);
  const float4 b0 = *(const float4*)(P1 + (size_t)qi * 2048 + cs);
  const float4 b1 = *(const float4*)(P1 + (size_t)qi * 2048 + cs + 4);
  bf16x8 o;
  o[0] = (bf16)((a0.x + b0.x) * linv); o[1] = (bf16)((a0.y + b0.y) * linv);
  o[2] = (bf16)((a0.z + b0.z) * linv); o[3] = (bf16)((a0.w + b0.w) * linv);
  o[4] = (bf16)((a1.x + b1.x) * linv); o[5] = (bf16)((a1.y + b1.y) * linv);
  o[6] = (bf16)((a1.z + b1.z) * linv); o[7] = (bf16)((a1.w + b1.w) * linv);
  *(bf16x8*)(AO + (size_t)qi * 2048 + cs) = o;
}

extern "C" void kernel_launch(void* const* d_in, const int* in_sizes, int n_in,
                              void* d_out, int out_size, void* d_ws,
                              size_t ws_size, hipStream_t stream) {
  (void)in_sizes; (void)n_in; (void)out_size; (void)ws_size;
  const float* x = (const float*)d_in[0];
  const float* Wq = (const float*)d_in[1];
  const float* Wk = (const float*)d_in[2];
  const float* Wv = (const float*)d_in[3];
  const float* Wo = (const float*)d_in[4];
  float* out = (float*)d_out;

  const size_t NE = (size_t)2048 * 2048;
  bf16* xb = (bf16*)d_ws;              // 8 MB (reused as OpA lo half)
  bf16* Wqb = xb + NE;                 // 8 MB (reused as OpA hi half)
  bf16* Wob = Wqb + NE;                // 8 MB
  bf16* Qb = Wob + NE;                 // 8 MB (reused as AO after attn)
  float* Kf = (float*)(Qb + NE);       // 512 KB (reused as lpart, both halves)
  float* Vf = Kf + 2048 * 64;          // 512 KB (reused as schedule table)
  bf16* Kb = (bf16*)(Vf + 2048 * 64);  // 256 KB
  bf16* Vtb = Kb + 2048 * 64;          // 256 KB  (end of ws usage: ~33.5 MB)
  float* OpA = (float*)d_ws;           // 16 MB f32, over xb+Wqb (dead by attn)
  float* OpB = out;                    // 16 MB f32 scratch (out written last)
  float* lpart = Kf;                   // 512 KB f32 (l0 + l1), over Kf
  uint32_t* tbl = (uint32_t*)Vf;       // 4 KB, over Vf (dead after pack_kv)
  bf16* AO = Qb;                       // normalize output (Q dead after attn)

  (void)hipMemsetAsync(Kf, 0, 2 * 2048 * 64 * sizeof(float), stream);
  conv3<<<dim3(2048, 3), 256, 0, stream>>>(x, xb, Wq, Wqb, Wo, Wob);
  gemm_bt_a<bf16><<<dim3(16, 32), 256, 0, stream>>>(xb, Wqb, Qb, 2048, 2048, 2048);
  kv_gemm<<<dim3(8, 16), 256, 0, stream>>>(xb, Wk, Wv, Kf, Vf);
  pack_kv<<<512, 256, 0, stream>>>(Kf, Vf, Kb, Vtb);
  mktable<<<1, 1024, 0, stream>>>(tbl);
  attn_kernel<<<1024, 512, 0, stream>>>(Qb, Kb, Vtb, OpA, OpB, lpart, tbl);
  norm_o<<<2048, 256, 0, stream>>>(OpA, OpB, lpart, AO);
  gemm_bt_a<float><<<dim3(16, 32), 256, 0, stream>>>(AO, Wob, out, 2048, 2048, 2048);
}

// Round 14
// 224.998 us; speedup vs baseline: 2.2487x; 1.0538x over previous
//
#include <hip/hip_runtime.h>
#include <stdint.h>
#include <math.h>

typedef __bf16 bf16;
typedef __bf16 bf16x4 __attribute__((ext_vector_type(4)));
typedef __bf16 bf16x8 __attribute__((ext_vector_type(8)));
typedef short short4v __attribute__((ext_vector_type(4)));
typedef float floatx4 __attribute__((ext_vector_type(4)));

#define MFMA32(a, b, c) __builtin_amdgcn_mfma_f32_16x16x32_bf16((a), (b), (c), 0, 0, 0)

__device__ __forceinline__ floatx4 mfma16(bf16x4 a, bf16x4 b, floatx4 c) {
  return __builtin_amdgcn_mfma_f32_16x16x16bf16_1k(
      __builtin_bit_cast(short4v, a), __builtin_bit_cast(short4v, b), c, 0, 0, 0);
}

__device__ __forceinline__ void gload16(const void* g, void* l) {
  __builtin_amdgcn_global_load_lds(
      (const __attribute__((address_space(1))) void*)g,
      (__attribute__((address_space(3))) void*)l, 16, 0, 0);
}

__device__ __forceinline__ bf16x8 load8(const float* p) {
  float4 lo = *(const float4*)p;
  float4 hi = *(const float4*)(p + 4);
  bf16x8 r;
  r[0] = (bf16)lo.x; r[1] = (bf16)lo.y; r[2] = (bf16)lo.z; r[3] = (bf16)lo.w;
  r[4] = (bf16)hi.x; r[5] = (bf16)hi.y; r[6] = (bf16)hi.z; r[7] = (bf16)hi.w;
  return r;
}

// One launch converting x, Wq, Wo to bf16. grid (2048, 3), 8 elems/thread.
__global__ __launch_bounds__(256) void conv3(const float* __restrict__ a, bf16* __restrict__ ab,
                                             const float* __restrict__ b, bf16* __restrict__ bb,
                                             const float* __restrict__ c, bf16* __restrict__ cb) {
  const int i = blockIdx.x * 256 + threadIdx.x;
  const float* src = blockIdx.y == 0 ? a : (blockIdx.y == 1 ? b : c);
  bf16* dst = blockIdx.y == 0 ? ab : (blockIdx.y == 1 ? bb : cb);
  ((bf16x8*)dst)[i] = load8(src + (size_t)i * 8);
}

// R14: fused Q-projection GEMM (blocks 0..511) + K/V projection (512..639).
// The two are independent (both read conv3 outputs, write disjoint buffers);
// merging hides kv's ~10us under the grid-limited Q-gemm (512 blocks = 2/CU
// with idle issue slots). Merged VGPR = max of branches, but grid is
// residency-limited (2.5 blocks/CU) well below resource limits -> no loss.
__global__ __launch_bounds__(256) void qkv_gemm(const bf16* __restrict__ xb,
                                                const bf16* __restrict__ Wqb,
                                                bf16* __restrict__ Qb,
                                                const float* __restrict__ Wk,
                                                const float* __restrict__ Wv,
                                                float* __restrict__ Kf,
                                                float* __restrict__ Vf) {
  __shared__ __align__(16) bf16 smem[12288];  // 24.5KB = max(gemm 12288, kv 10240)
  const int tid = threadIdx.x;
  const int wave = tid >> 6, lane = tid & 63;
  const int quad = lane >> 4, l16 = lane & 15;

  if (blockIdx.x < 512) {
    // ---- Q-proj: C[2048,2048] = xb @ Wqb^T (R11-verified body) ----
    const int K = 2048, N = 2048;
    bf16* const As0 = smem;         // [2][64*32]
    bf16* const Bs0 = smem + 4096;  // [2][128*32]
    const int wg = blockIdx.x;
    const int wgid = (wg & 7) * 64 + (wg >> 3);  // XCD remap (bijective)
    const int m0 = (wgid >> 4) * 64, n0 = (wgid & 15) * 128;
    const int wm = (wave >> 1) * 32, wn = (wave & 1) * 64;

    floatx4 acc[2][4];
#pragma unroll
    for (int i = 0; i < 2; i++)
#pragma unroll
      for (int j = 0; j < 4; j++) acc[i][j] = (floatx4)0.f;

    const int srow = tid >> 2;
    const int scol = ((tid & 3) ^ ((tid >> 3) & 3)) * 8;  // pre-swizzled src
    const bf16* Ap = xb + (size_t)(m0 + srow) * K + scol;
    const bf16* Bp = Wqb + (size_t)(n0 + srow) * K + scol;

    auto stage = [&](int k0, int buf) {
      gload16(Ap + k0, (char*)(As0 + buf * 2048) + tid * 16);
      gload16(Bp + k0, (char*)(Bs0 + buf * 4096) + tid * 16);
      gload16(Bp + (size_t)64 * K + k0, (char*)(Bs0 + buf * 4096) + 4096 + tid * 16);
    };
    const int sxg = (l16 >> 1) & 3;
    auto compute = [&](int buf) {
      bf16x8 af[2], bfr[4];
#pragma unroll
      for (int mt = 0; mt < 2; mt++)
        af[mt] = *(const bf16x8*)(&(As0 + buf * 2048)[(wm + mt * 16 + l16) * 32 + ((quad ^ sxg) * 8)]);
#pragma unroll
      for (int nt = 0; nt < 4; nt++)
        bfr[nt] = *(const bf16x8*)(&(Bs0 + buf * 4096)[(wn + nt * 16 + l16) * 32 + ((quad ^ sxg) * 8)]);
#pragma unroll
      for (int mt = 0; mt < 2; mt++)
#pragma unroll
        for (int nt = 0; nt < 4; nt++)
          acc[mt][nt] = MFMA32(af[mt], bfr[nt], acc[mt][nt]);
    };

    stage(0, 0);
    for (int k0 = 0; k0 < K; k0 += 64) {
      __syncthreads();
      if (k0 + 32 < K) stage(k0 + 32, 1);
      compute(0);
      __syncthreads();
      if (k0 + 64 < K) stage(k0 + 64, 0);
      compute(1);
    }

#pragma unroll
    for (int mt = 0; mt < 2; mt++) {
#pragma unroll
      for (int nt = 0; nt < 4; nt++) {
        const int col = n0 + wn + nt * 16 + l16;
        const int row = m0 + wm + mt * 16 + quad * 4;
#pragma unroll
        for (int r = 0; r < 4; r++)
          Qb[(size_t)(row + r) * N + col] = (bf16)acc[mt][nt][r];
      }
    }
  } else {
    // ---- K/V proj, split-K x8 (R7-verified kv_gemm body) ----
    bf16* const As2 = smem;         // [128*40]
    bf16* const Bs2 = smem + 5120;  // [128*40]
    const int bid = (int)blockIdx.x - 512;
    const int m0 = (bid >> 3) * 128;
    const int kbeg = (bid & 7) * 256, kend = kbeg + 256;
    const int wm = (wave >> 1) * 64, wn = (wave & 1) * 64;

    floatx4 acc[4][4];
#pragma unroll
    for (int i = 0; i < 4; i++)
#pragma unroll
      for (int j = 0; j < 4; j++) acc[i][j] = (floatx4)0.f;

    const int sr = tid >> 2, sc = (tid & 3) * 8;

    for (int k0 = kbeg; k0 < kend; k0 += 32) {
      __syncthreads();
#pragma unroll
      for (int rr = 0; rr < 2; rr++) {
        const int row = sr + rr * 64;
        *(bf16x8*)(&As2[row * 40 + sc]) =
            *(const bf16x8*)(&xb[(size_t)(m0 + row) * 2048 + k0 + sc]);
        const float* bsrc = (row < 64) ? &Wk[(size_t)row * 2048 + k0 + sc]
                                       : &Wv[(size_t)(row - 64) * 2048 + k0 + sc];
        *(bf16x8*)(&Bs2[row * 40 + sc]) = load8(bsrc);
      }
      __syncthreads();

      bf16x8 af[4], bfr[4];
#pragma unroll
      for (int mt = 0; mt < 4; mt++)
        af[mt] = *(const bf16x8*)(&As2[(wm + mt * 16 + l16) * 40 + quad * 8]);
#pragma unroll
      for (int nt = 0; nt < 4; nt++)
        bfr[nt] = *(const bf16x8*)(&Bs2[(wn + nt * 16 + l16) * 40 + quad * 8]);
#pragma unroll
      for (int mt = 0; mt < 4; mt++)
#pragma unroll
        for (int nt = 0; nt < 4; nt++)
          acc[mt][nt] = MFMA32(af[mt], bfr[nt], acc[mt][nt]);
    }

#pragma unroll
    for (int mt = 0; mt < 4; mt++) {
#pragma unroll
      for (int nt = 0; nt < 4; nt++) {
        const int col = wn + nt * 16 + l16;
        const int row = m0 + wm + mt * 16 + quad * 4;
        float* dst = (col < 64) ? &Kf[(size_t)row * 64 + col]
                                : &Vf[(size_t)row * 64 + (col - 64)];
#pragma unroll
        for (int r = 0; r < 4; r++) atomicAdd(dst + (size_t)r * 64, acc[mt][nt][r]);
      }
    }
  }
}

// C[M,N] = A[M,K] @ B[N,K]^T (out-projection). R11-verified.
template <typename TC>
__global__ __launch_bounds__(256) void gemm_bt_a(const bf16* __restrict__ A,
                                                 const bf16* __restrict__ B,
                                                 TC* __restrict__ C,
                                                 int M, int N, int K) {
  __shared__ __align__(16) bf16 As[2][64 * 32];
  __shared__ __align__(16) bf16 Bs[2][128 * 32];
  const int tid = threadIdx.x;
  const int wave = tid >> 6, lane = tid & 63;
  const int quad = lane >> 4, l16 = lane & 15;
  const int wg = blockIdx.y * 16 + blockIdx.x;
  const int wgid = (wg & 7) * 64 + (wg >> 3);
  const int m0 = (wgid >> 4) * 64, n0 = (wgid & 15) * 128;
  const int wm = (wave >> 1) * 32, wn = (wave & 1) * 64;

  floatx4 acc[2][4];
#pragma unroll
  for (int i = 0; i < 2; i++)
#pragma unroll
    for (int j = 0; j < 4; j++) acc[i][j] = (floatx4)0.f;

  const int srow = tid >> 2;
  const int scol = ((tid & 3) ^ ((tid >> 3) & 3)) * 8;
  const bf16* Ap = A + (size_t)(m0 + srow) * K + scol;
  const bf16* Bp = B + (size_t)(n0 + srow) * K + scol;

  auto stage = [&](int k0, int buf) {
    gload16(Ap + k0, (char*)As[buf] + tid * 16);
    gload16(Bp + k0, (char*)Bs[buf] + tid * 16);
    gload16(Bp + (size_t)64 * K + k0, (char*)Bs[buf] + 4096 + tid * 16);
  };
  const int sxg = (l16 >> 1) & 3;
  auto compute = [&](int buf) {
    bf16x8 af[2], bfr[4];
#pragma unroll
    for (int mt = 0; mt < 2; mt++)
      af[mt] = *(const bf16x8*)(&As[buf][(wm + mt * 16 + l16) * 32 + ((quad ^ sxg) * 8)]);
#pragma unroll
    for (int nt = 0; nt < 4; nt++)
      bfr[nt] = *(const bf16x8*)(&Bs[buf][(wn + nt * 16 + l16) * 32 + ((quad ^ sxg) * 8)]);
#pragma unroll
    for (int mt = 0; mt < 2; mt++)
#pragma unroll
      for (int nt = 0; nt < 4; nt++)
        acc[mt][nt] = MFMA32(af[mt], bfr[nt], acc[mt][nt]);
  };

  stage(0, 0);
  for (int k0 = 0; k0 < K; k0 += 64) {
    __syncthreads();
    if (k0 + 32 < K) stage(k0 + 32, 1);
    compute(0);
    __syncthreads();
    if (k0 + 64 < K) stage(k0 + 64, 0);
    compute(1);
  }

#pragma unroll
  for (int mt = 0; mt < 2; mt++) {
#pragma unroll
    for (int nt = 0; nt < 4; nt++) {
      const int col = n0 + wn + nt * 16 + l16;
      const int row = m0 + wm + mt * 16 + quad * 4;
#pragma unroll
      for (int r = 0; r < 4; r++)
        C[(size_t)(row + r) * N + col] = (TC)acc[mt][nt][r];
    }
  }
}

#define WTHR 30.f

// R14: fused pack_kv (blocks 0..511) + mktable (block 512, 256 thr x 4
// items). Disjoint outputs, same dependency (kv done).
__global__ __launch_bounds__(256) void pack_mk(const float* __restrict__ Kf,
                                               const float* __restrict__ Vf,
                                               bf16* __restrict__ Kb,
                                               bf16* __restrict__ Vtb,
                                               uint32_t* __restrict__ tbl) {
  __shared__ int bins[17], base[17];
  const int tid = threadIdx.x;
  if (blockIdx.x < 512) {
    const int i = blockIdx.x * 256 + tid;
    if (i < 2048 * 64) {
      Kb[i] = (bf16)Kf[i];
      const int t = i >> 6, d = i & 63;
      Vtb[(size_t)d * 2048 + t] = (bf16)Vf[i];
    }
  } else {
    int loads[4];
    if (tid < 17) bins[tid] = 0;
    __syncthreads();
#pragma unroll
    for (int k = 0; k < 4; k++) {
      const int idx = tid + k * 256;
      const int p = idx & 511, hf = idx >> 9;
      const int h = p & 31, t = p >> 5;
      const float slope2 = exp2f(-0.25f * (float)(h + 1)) * 1.44269504f;
      const int lo_key = t * 128 - (int)(WTHR / slope2);
      const int lo_t = (lo_key <= 0) ? 0 : (lo_key >> 6);
      const int m = 2 * t + 2 - lo_t;
      loads[k] = hf ? (m >> 1) : ((m + 1) >> 1);
      atomicAdd(&bins[loads[k]], 1);
    }
    __syncthreads();
    if (tid == 0) {  // descending prefix: base[v] = # blocks with load > v
      int s = 0;
      for (int v = 16; v >= 0; --v) { base[v] = s; s += bins[v]; }
    }
    __syncthreads();
    if (tid < 17) bins[tid] = 0;
    __syncthreads();
#pragma unroll
    for (int k = 0; k < 4; k++) {
      const int idx = tid + k * 256;
      const int off = atomicAdd(&bins[loads[k]], 1);
      tbl[base[loads[k]] + off] = (uint32_t)(((idx >> 9) << 9) | (idx & 511));
    }
  }
}

// Flash attention, deterministic 2-way split per (h, q-tile) — R7/R11-
// verified structure (best measured; setprio was null, dropped). 1024
// blocks x 512 thr, ALL co-resident (32KB LDS, 60 VGPR -> 4 blocks/CU).
// bid folds to load rank {u, 511-u, 512+u, 1023-u}. Halves store partials
// to OpA / OpB (plain f32 stores, exactly once).
__global__ __launch_bounds__(512) void attn_kernel(const bf16* __restrict__ Q,
                                                   const bf16* __restrict__ Kb,
                                                   const bf16* __restrict__ Vtb,
                                                   float* __restrict__ OpA,
                                                   float* __restrict__ OpB,
                                                   float* __restrict__ lpart,
                                                   const uint32_t* __restrict__ tbl) {
  __shared__ __align__(16) bf16 Ks[2][64 * 64];  // [buf][key][d] swizzled
  __shared__ __align__(16) bf16 Vt[2][64 * 64];  // [buf][d][key] swizzled

  const int u = blockIdx.x & 255, sfold = blockIdx.x >> 8;
  const int r = (sfold == 0) ? u : (sfold == 1) ? (511 - u)
                : (sfold == 2) ? (512 + u) : (1023 - u);
  const uint32_t e = tbl[r];
  const int p = e & 511, hf = (int)(e >> 9);
  const int h = p & 31, t = p >> 5;

  const float slope2 = exp2f(-0.25f * (float)(h + 1)) * 1.44269504f;
  const int lo_key = t * 128 - (int)(WTHR / slope2);
  const int lo_t = (lo_key <= 0) ? 0 : (lo_key >> 6);
  const int m = 2 * t + 2 - lo_t;        // >= 2
  const int c0 = (m + 1) >> 1;
  const int kbeg = hf ? (lo_t + c0) : lo_t;
  const int cnt = hf ? (m >> 1) : c0;    // >= 1 always

  const int tid = threadIdx.x;
  const int wave = tid >> 6;  // 0..7 -> q-rows wave*16..+15
  const int lane = tid & 63;
  const int quad = lane >> 4, l16 = lane & 15;
  const float scale2 = 0.125f * 1.44269504f;
  const bf16x4 ones = {(bf16)1.f, (bf16)1.f, (bf16)1.f, (bf16)1.f};

  float cq[4];
#pragma unroll
  for (int rr = 0; rr < 4; rr++) cq[rr] = slope2 * (float)(quad * 4 + rr);
  const float s16 = slope2 * 16.f;

  const int qi = t * 128 + wave * 16 + l16;
  const int qw0 = t * 128 + wave * 16;
  bf16x8 qf[2];
#pragma unroll
  for (int kk = 0; kk < 2; kk++)
    qf[kk] = *(const bf16x8*)(&Q[(size_t)qi * 2048 + h * 64 + kk * 32 + quad * 8]);

  floatx4 oacc[4];
#pragma unroll
  for (int dt = 0; dt < 4; dt++) oacc[dt] = (floatx4)0.f;
  floatx4 lacc = (floatx4)0.f;

  // staging: 512 threads stage 64x64 K and V tiles (one bf16x8 each)
  const int r0 = tid >> 3, sl = tid & 7;     // row 0..63, 16B slot 0..7
  const int wsw = ((sl ^ (r0 & 7)) << 3);    // XOR-swizzled elem offset
  const int sx = l16 & 7;                    // read-side swizzle bits

  const int kn = kbeg * 64;
  bf16x8 kreg = *(const bf16x8*)(&Kb[(size_t)(kn + r0) * 64 + sl * 8]);
  bf16x8 vreg = *(const bf16x8*)(&Vtb[(size_t)r0 * 2048 + kn + sl * 8]);

  for (int i = 0; i < cnt; i++) {
    const int kt = kbeg + i;
    const int buf = i & 1;
    *(bf16x8*)(&Ks[buf][r0 * 64 + wsw]) = kreg;
    *(bf16x8*)(&Vt[buf][r0 * 64 + wsw]) = vreg;
    __syncthreads();  // tile kt visible
    if (i + 1 < cnt) {  // prefetch next tile (kt+1 <= 31 by construction)
      const int kn2 = (kt + 1) * 64;
      kreg = *(const bf16x8*)(&Kb[(size_t)(kn2 + r0) * 64 + sl * 8]);
      vreg = *(const bf16x8*)(&Vtb[(size_t)r0 * 2048 + kn2 + sl * 8]);
    }
    const int k0 = kt * 64;
    if (k0 > qw0 + 15) continue;                               // causal skip
    if ((float)(qw0 - k0 - 63) * slope2 > WTHR) continue;      // ALiBi window

    const bf16* ks = Ks[buf];
    const bf16* vs = Vt[buf];

    // S^T[key][q] = K . Q^T
    floatx4 s[4];
#pragma unroll
    for (int mt = 0; mt < 4; mt++) s[mt] = (floatx4)0.f;
#pragma unroll
    for (int kk = 0; kk < 2; kk++) {
#pragma unroll
      for (int mt = 0; mt < 4; mt++) {
        bf16x8 kf = *(const bf16x8*)(
            &ks[(mt * 16 + l16) * 64 + (((kk * 4 + quad) ^ sx) << 3)]);
        s[mt] = MFMA32(kf, qf[kk], s[mt]);
      }
    }

    // p = exp2(s*scale2 + slope2*(j-i)); scores bounded -> no running max
    const float base0 = slope2 * (float)(k0 - qi);
    bf16x4 pb[4];
    if (k0 + 63 <= qw0) {  // interior for the whole wave: no mask
      float b = base0;
#pragma unroll
      for (int mt = 0; mt < 4; mt++) {
        bf16x4 tb;
#pragma unroll
        for (int rr = 0; rr < 4; rr++)
          tb[rr] = (bf16)exp2f(__builtin_fmaf(s[mt][rr], scale2, b + cq[rr]));
        pb[mt] = tb;
        b += s16;
      }
    } else {  // diagonal tile: per-lane causal mask
      const int qloc = qi - k0;
      float b = base0;
#pragma unroll
      for (int mt = 0; mt < 4; mt++) {
        bf16x4 tb;
#pragma unroll
        for (int rr = 0; rr < 4; rr++) {
          const int moff = mt * 16 + quad * 4 + rr;
          const float pv = exp2f(__builtin_fmaf(s[mt][rr], scale2, b + cq[rr]));
          tb[rr] = (moff <= qloc) ? (bf16)pv : (bf16)0.f;
        }
        pb[mt] = tb;
        b += s16;
      }
    }

    // O^T[d][q] += V^T . P^T ; l += 1 . P^T (matrix-pipe row-sum)
#pragma unroll
    for (int mt = 0; mt < 4; mt++) {
      lacc = mfma16(ones, pb[mt], lacc);
#pragma unroll
      for (int dt = 0; dt < 4; dt++) {
        const int slot = 2 * mt + (quad >> 1);
        const bf16x4 va = *(const bf16x4*)(
            &vs[(dt * 16 + l16) * 64 + ((slot ^ sx) << 3) + (quad & 1) * 4]);
        oacc[dt] = mfma16(va, pb[mt], oacc[dt]);
      }
    }
  }

  // flush partial (plain f32 stores; each slot written exactly once)
  float* op = (hf ? OpB : OpA) + (size_t)qi * 2048 + h * 64;
#pragma unroll
  for (int dt = 0; dt < 4; dt++)
#pragma unroll
    for (int rr = 0; rr < 4; rr++)
      op[dt * 16 + quad * 4 + rr] = oacc[dt][rr];
  if (quad == 0) lpart[(size_t)hf * 65536 + (size_t)qi * 32 + h] = lacc[0];
}

// AO[qi][e] = (P0+P1)[qi][e] / (l0+l1)[qi][e>>6], bf16. 2048 blocks x 256.
__global__ __launch_bounds__(256) void norm_o(const float* __restrict__ P0,
                                              const float* __restrict__ P1,
                                              const float* __restrict__ L,
                                              bf16* __restrict__ AO) {
  const int idx = blockIdx.x * 256 + threadIdx.x;
  const int qi = idx >> 8;
  const int cs = (idx & 255) << 3;
  const int h = cs >> 6;
  const float l = L[(size_t)qi * 32 + h] + L[65536 + (size_t)qi * 32 + h];
  const float linv = 1.f / l;
  const float4 a0 = *(const float4*)(P0 + (size_t)qi * 2048 + cs);
  const float4 a1 = *(const float4*)(P0 + (size_t)qi * 2048 + cs + 4);
  const float4 b0 = *(const float4*)(P1 + (size_t)qi * 2048 + cs);
  const float4 b1 = *(const float4*)(P1 + (size_t)qi * 2048 + cs + 4);
  bf16x8 o;
  o[0] = (bf16)((a0.x + b0.x) * linv); o[1] = (bf16)((a0.y + b0.y) * linv);
  o[2] = (bf16)((a0.z + b0.z) * linv); o[3] = (bf16)((a0.w + b0.w) * linv);
  o[4] = (bf16)((a1.x + b1.x) * linv); o[5] = (bf16)((a1.y + b1.y) * linv);
  o[6] = (bf16)((a1.z + b1.z) * linv); o[7] = (bf16)((a1.w + b1.w) * linv);
  *(bf16x8*)(AO + (size_t)qi * 2048 + cs) = o;
}

extern "C" void kernel_launch(void* const* d_in, const int* in_sizes, int n_in,
                              void* d_out, int out_size, void* d_ws,
                              size_t ws_size, hipStream_t stream) {
  (void)in_sizes; (void)n_in; (void)out_size; (void)ws_size;
  const float* x = (const float*)d_in[0];
  const float* Wq = (const float*)d_in[1];
  const float* Wk = (const float*)d_in[2];
  const float* Wv = (const float*)d_in[3];
  const float* Wo = (const float*)d_in[4];
  float* out = (float*)d_out;

  const size_t NE = (size_t)2048 * 2048;
  bf16* xb = (bf16*)d_ws;              // 8 MB (reused as OpA lo half)
  bf16* Wqb = xb + NE;                 // 8 MB (reused as OpA hi half)
  bf16* Wob = Wqb + NE;                // 8 MB
  bf16* Qb = Wob + NE;                 // 8 MB (reused as AO after attn)
  float* Kf = (float*)(Qb + NE);       // 512 KB (reused as lpart, both halves)
  float* Vf = Kf + 2048 * 64;          // 512 KB (reused as schedule table)
  bf16* Kb = (bf16*)(Vf + 2048 * 64);  // 256 KB
  bf16* Vtb = Kb + 2048 * 64;          // 256 KB  (end of ws usage: ~33.5 MB)
  float* OpA = (float*)d_ws;           // 16 MB f32, over xb+Wqb (dead by attn)
  float* OpB = out;                    // 16 MB f32 scratch (out written last)
  float* lpart = Kf;                   // 512 KB f32 (l0 + l1), over Kf
  uint32_t* tbl = (uint32_t*)Vf;       // 4 KB, over Vf (dead after pack_mk)
  bf16* AO = Qb;                       // normalize output (Q dead after attn)

  (void)hipMemsetAsync(Kf, 0, 2 * 2048 * 64 * sizeof(float), stream);
  conv3<<<dim3(2048, 3), 256, 0, stream>>>(x, xb, Wq, Wqb, Wo, Wob);
  qkv_gemm<<<640, 256, 0, stream>>>(xb, Wqb, Qb, Wk, Wv, Kf, Vf);
  pack_mk<<<513, 256, 0, stream>>>(Kf, Vf, Kb, Vtb, tbl);
  attn_kernel<<<1024, 512, 0, stream>>>(Qb, Kb, Vtb, OpA, OpB, lpart, tbl);
  norm_o<<<2048, 256, 0, stream>>>(OpA, OpB, lpart, AO);
  gemm_bt_a<float><<<dim3(16, 32), 256, 0, stream>>>(AO, Wob, out, 2048, 2048, 2048);
}

// Round 15
// 222.518 us; speedup vs baseline: 2.2738x; 1.0111x over previous
//
#include <hip/hip_runtime.h>
#include <stdint.h>
#include <math.h>

typedef __bf16 bf16;
typedef __bf16 bf16x4 __attribute__((ext_vector_type(4)));
typedef __bf16 bf16x8 __attribute__((ext_vector_type(8)));
typedef short short4v __attribute__((ext_vector_type(4)));
typedef float floatx4 __attribute__((ext_vector_type(4)));

#define MFMA32(a, b, c) __builtin_amdgcn_mfma_f32_16x16x32_bf16((a), (b), (c), 0, 0, 0)

__device__ __forceinline__ floatx4 mfma16(bf16x4 a, bf16x4 b, floatx4 c) {
  return __builtin_amdgcn_mfma_f32_16x16x16bf16_1k(
      __builtin_bit_cast(short4v, a), __builtin_bit_cast(short4v, b), c, 0, 0, 0);
}

__device__ __forceinline__ void gload16(const void* g, void* l) {
  __builtin_amdgcn_global_load_lds(
      (const __attribute__((address_space(1))) void*)g,
      (__attribute__((address_space(3))) void*)l, 16, 0, 0);
}

__device__ __forceinline__ bf16x8 load8(const float* p) {
  float4 lo = *(const float4*)p;
  float4 hi = *(const float4*)(p + 4);
  bf16x8 r;
  r[0] = (bf16)lo.x; r[1] = (bf16)lo.y; r[2] = (bf16)lo.z; r[3] = (bf16)lo.w;
  r[4] = (bf16)hi.x; r[5] = (bf16)hi.y; r[6] = (bf16)hi.z; r[7] = (bf16)hi.w;
  return r;
}

// R15 prep: convert x (blocks 0..2047) and Wq (2048..4095) to bf16, and
// zero the contiguous Kf|Vf accumulator region (4096..4351) — replaces
// conv3's x/Wq thirds + the hipMemsetAsync. Wo conversion moved into the
// qkv_gemm launch (it's only needed by the final GEMM).
__global__ __launch_bounds__(256) void prep(const float* __restrict__ x,
                                            bf16* __restrict__ xb,
                                            const float* __restrict__ Wq,
                                            bf16* __restrict__ Wqb,
                                            float* __restrict__ Kf) {
  const int b = blockIdx.x;
  const int tid = threadIdx.x;
  if (b < 4096) {
    const bool first = (b < 2048);
    const float* src = first ? x : Wq;
    bf16* dst = first ? xb : Wqb;
    const int j = (first ? b : b - 2048) * 256 + tid;
    ((bf16x8*)dst)[j] = load8(src + (size_t)j * 8);
  } else {
    const int j = (b - 4096) * 256 + tid;  // 65536 float4 = 1MB (Kf+Vf)
    float4 z; z.x = 0.f; z.y = 0.f; z.z = 0.f; z.w = 0.f;
    ((float4*)Kf)[j] = z;
  }
}

// R14/R15 fused launch: Q-projection GEMM (blocks 0..511, R11-verified
// body) + K/V projection split-K x8 (512..639, R7-verified body) + Wo
// f32->bf16 conversion (640..2687 — independent of conv outputs, rides in
// the GEMM's latency shadow; gemm blocks dispatch first so no tail).
__global__ __launch_bounds__(256) void qkv_gemm(const bf16* __restrict__ xb,
                                                const bf16* __restrict__ Wqb,
                                                bf16* __restrict__ Qb,
                                                const float* __restrict__ Wk,
                                                const float* __restrict__ Wv,
                                                float* __restrict__ Kf,
                                                float* __restrict__ Vf,
                                                const float* __restrict__ Wo,
                                                bf16* __restrict__ Wob) {
  __shared__ __align__(16) bf16 smem[12288];  // 24.5KB = max(gemm, kv)
  const int tid = threadIdx.x;
  const int wave = tid >> 6, lane = tid & 63;
  const int quad = lane >> 4, l16 = lane & 15;

  if (blockIdx.x >= 640) {
    // ---- Wo conversion (2048 blocks x 2048 elems) ----
    const int i = ((int)blockIdx.x - 640) * 256 + tid;
    ((bf16x8*)Wob)[i] = load8(Wo + (size_t)i * 8);
    return;
  }

  if (blockIdx.x < 512) {
    // ---- Q-proj: C[2048,2048] = xb @ Wqb^T ----
    const int K = 2048, N = 2048;
    bf16* const As0 = smem;         // [2][64*32]
    bf16* const Bs0 = smem + 4096;  // [2][128*32]
    const int wg = blockIdx.x;
    const int wgid = (wg & 7) * 64 + (wg >> 3);  // XCD remap (bijective)
    const int m0 = (wgid >> 4) * 64, n0 = (wgid & 15) * 128;
    const int wm = (wave >> 1) * 32, wn = (wave & 1) * 64;

    floatx4 acc[2][4];
#pragma unroll
    for (int i = 0; i < 2; i++)
#pragma unroll
      for (int j = 0; j < 4; j++) acc[i][j] = (floatx4)0.f;

    const int srow = tid >> 2;
    const int scol = ((tid & 3) ^ ((tid >> 3) & 3)) * 8;  // pre-swizzled src
    const bf16* Ap = xb + (size_t)(m0 + srow) * K + scol;
    const bf16* Bp = Wqb + (size_t)(n0 + srow) * K + scol;

    auto stage = [&](int k0, int buf) {
      gload16(Ap + k0, (char*)(As0 + buf * 2048) + tid * 16);
      gload16(Bp + k0, (char*)(Bs0 + buf * 4096) + tid * 16);
      gload16(Bp + (size_t)64 * K + k0, (char*)(Bs0 + buf * 4096) + 4096 + tid * 16);
    };
    const int sxg = (l16 >> 1) & 3;
    auto compute = [&](int buf) {
      bf16x8 af[2], bfr[4];
#pragma unroll
      for (int mt = 0; mt < 2; mt++)
        af[mt] = *(const bf16x8*)(&(As0 + buf * 2048)[(wm + mt * 16 + l16) * 32 + ((quad ^ sxg) * 8)]);
#pragma unroll
      for (int nt = 0; nt < 4; nt++)
        bfr[nt] = *(const bf16x8*)(&(Bs0 + buf * 4096)[(wn + nt * 16 + l16) * 32 + ((quad ^ sxg) * 8)]);
#pragma unroll
      for (int mt = 0; mt < 2; mt++)
#pragma unroll
        for (int nt = 0; nt < 4; nt++)
          acc[mt][nt] = MFMA32(af[mt], bfr[nt], acc[mt][nt]);
    };

    stage(0, 0);
    for (int k0 = 0; k0 < K; k0 += 64) {
      __syncthreads();
      if (k0 + 32 < K) stage(k0 + 32, 1);
      compute(0);
      __syncthreads();
      if (k0 + 64 < K) stage(k0 + 64, 0);
      compute(1);
    }

#pragma unroll
    for (int mt = 0; mt < 2; mt++) {
#pragma unroll
      for (int nt = 0; nt < 4; nt++) {
        const int col = n0 + wn + nt * 16 + l16;
        const int row = m0 + wm + mt * 16 + quad * 4;
#pragma unroll
        for (int r = 0; r < 4; r++)
          Qb[(size_t)(row + r) * N + col] = (bf16)acc[mt][nt][r];
      }
    }
  } else {
    // ---- K/V proj, split-K x8 ----
    bf16* const As2 = smem;         // [128*40]
    bf16* const Bs2 = smem + 5120;  // [128*40]
    const int bid = (int)blockIdx.x - 512;
    const int m0 = (bid >> 3) * 128;
    const int kbeg = (bid & 7) * 256, kend = kbeg + 256;
    const int wm = (wave >> 1) * 64, wn = (wave & 1) * 64;

    floatx4 acc[4][4];
#pragma unroll
    for (int i = 0; i < 4; i++)
#pragma unroll
      for (int j = 0; j < 4; j++) acc[i][j] = (floatx4)0.f;

    const int sr = tid >> 2, sc = (tid & 3) * 8;

    for (int k0 = kbeg; k0 < kend; k0 += 32) {
      __syncthreads();
#pragma unroll
      for (int rr = 0; rr < 2; rr++) {
        const int row = sr + rr * 64;
        *(bf16x8*)(&As2[row * 40 + sc]) =
            *(const bf16x8*)(&xb[(size_t)(m0 + row) * 2048 + k0 + sc]);
        const float* bsrc = (row < 64) ? &Wk[(size_t)row * 2048 + k0 + sc]
                                       : &Wv[(size_t)(row - 64) * 2048 + k0 + sc];
        *(bf16x8*)(&Bs2[row * 40 + sc]) = load8(bsrc);
      }
      __syncthreads();

      bf16x8 af[4], bfr[4];
#pragma unroll
      for (int mt = 0; mt < 4; mt++)
        af[mt] = *(const bf16x8*)(&As2[(wm + mt * 16 + l16) * 40 + quad * 8]);
#pragma unroll
      for (int nt = 0; nt < 4; nt++)
        bfr[nt] = *(const bf16x8*)(&Bs2[(wn + nt * 16 + l16) * 40 + quad * 8]);
#pragma unroll
      for (int mt = 0; mt < 4; mt++)
#pragma unroll
        for (int nt = 0; nt < 4; nt++)
          acc[mt][nt] = MFMA32(af[mt], bfr[nt], acc[mt][nt]);
    }

#pragma unroll
    for (int mt = 0; mt < 4; mt++) {
#pragma unroll
      for (int nt = 0; nt < 4; nt++) {
        const int col = wn + nt * 16 + l16;
        const int row = m0 + wm + mt * 16 + quad * 4;
        float* dst = (col < 64) ? &Kf[(size_t)row * 64 + col]
                                : &Vf[(size_t)row * 64 + (col - 64)];
#pragma unroll
        for (int r = 0; r < 4; r++) atomicAdd(dst + (size_t)r * 64, acc[mt][nt][r]);
      }
    }
  }
}

// C[M,N] = A[M,K] @ B[N,K]^T (out-projection). R11-verified.
template <typename TC>
__global__ __launch_bounds__(256) void gemm_bt_a(const bf16* __restrict__ A,
                                                 const bf16* __restrict__ B,
                                                 TC* __restrict__ C,
                                                 int M, int N, int K) {
  __shared__ __align__(16) bf16 As[2][64 * 32];
  __shared__ __align__(16) bf16 Bs[2][128 * 32];
  const int tid = threadIdx.x;
  const int wave = tid >> 6, lane = tid & 63;
  const int quad = lane >> 4, l16 = lane & 15;
  const int wg = blockIdx.y * 16 + blockIdx.x;
  const int wgid = (wg & 7) * 64 + (wg >> 3);
  const int m0 = (wgid >> 4) * 64, n0 = (wgid & 15) * 128;
  const int wm = (wave >> 1) * 32, wn = (wave & 1) * 64;

  floatx4 acc[2][4];
#pragma unroll
  for (int i = 0; i < 2; i++)
#pragma unroll
    for (int j = 0; j < 4; j++) acc[i][j] = (floatx4)0.f;

  const int srow = tid >> 2;
  const int scol = ((tid & 3) ^ ((tid >> 3) & 3)) * 8;
  const bf16* Ap = A + (size_t)(m0 + srow) * K + scol;
  const bf16* Bp = B + (size_t)(n0 + srow) * K + scol;

  auto stage = [&](int k0, int buf) {
    gload16(Ap + k0, (char*)As[buf] + tid * 16);
    gload16(Bp + k0, (char*)Bs[buf] + tid * 16);
    gload16(Bp + (size_t)64 * K + k0, (char*)Bs[buf] + 4096 + tid * 16);
  };
  const int sxg = (l16 >> 1) & 3;
  auto compute = [&](int buf) {
    bf16x8 af[2], bfr[4];
#pragma unroll
    for (int mt = 0; mt < 2; mt++)
      af[mt] = *(const bf16x8*)(&As[buf][(wm + mt * 16 + l16) * 32 + ((quad ^ sxg) * 8)]);
#pragma unroll
    for (int nt = 0; nt < 4; nt++)
      bfr[nt] = *(const bf16x8*)(&Bs[buf][(wn + nt * 16 + l16) * 32 + ((quad ^ sxg) * 8)]);
#pragma unroll
    for (int mt = 0; mt < 2; mt++)
#pragma unroll
      for (int nt = 0; nt < 4; nt++)
        acc[mt][nt] = MFMA32(af[mt], bfr[nt], acc[mt][nt]);
  };

  stage(0, 0);
  for (int k0 = 0; k0 < K; k0 += 64) {
    __syncthreads();
    if (k0 + 32 < K) stage(k0 + 32, 1);
    compute(0);
    __syncthreads();
    if (k0 + 64 < K) stage(k0 + 64, 0);
    compute(1);
  }

#pragma unroll
  for (int mt = 0; mt < 2; mt++) {
#pragma unroll
    for (int nt = 0; nt < 4; nt++) {
      const int col = n0 + wn + nt * 16 + l16;
      const int row = m0 + wm + mt * 16 + quad * 4;
#pragma unroll
      for (int r = 0; r < 4; r++)
        C[(size_t)(row + r) * N + col] = (TC)acc[mt][nt][r];
    }
  }
}

#define WTHR 30.f

// Fused pack_kv (blocks 0..511) + mktable (block 512). R14-verified.
__global__ __launch_bounds__(256) void pack_mk(const float* __restrict__ Kf,
                                               const float* __restrict__ Vf,
                                               bf16* __restrict__ Kb,
                                               bf16* __restrict__ Vtb,
                                               uint32_t* __restrict__ tbl) {
  __shared__ int bins[17], base[17];
  const int tid = threadIdx.x;
  if (blockIdx.x < 512) {
    const int i = blockIdx.x * 256 + tid;
    if (i < 2048 * 64) {
      Kb[i] = (bf16)Kf[i];
      const int t = i >> 6, d = i & 63;
      Vtb[(size_t)d * 2048 + t] = (bf16)Vf[i];
    }
  } else {
    int loads[4];
    if (tid < 17) bins[tid] = 0;
    __syncthreads();
#pragma unroll
    for (int k = 0; k < 4; k++) {
      const int idx = tid + k * 256;
      const int p = idx & 511, hf = idx >> 9;
      const int h = p & 31, t = p >> 5;
      const float slope2 = exp2f(-0.25f * (float)(h + 1)) * 1.44269504f;
      const int lo_key = t * 128 - (int)(WTHR / slope2);
      const int lo_t = (lo_key <= 0) ? 0 : (lo_key >> 6);
      const int m = 2 * t + 2 - lo_t;
      loads[k] = hf ? (m >> 1) : ((m + 1) >> 1);
      atomicAdd(&bins[loads[k]], 1);
    }
    __syncthreads();
    if (tid == 0) {  // descending prefix: base[v] = # blocks with load > v
      int s = 0;
      for (int v = 16; v >= 0; --v) { base[v] = s; s += bins[v]; }
    }
    __syncthreads();
    if (tid < 17) bins[tid] = 0;
    __syncthreads();
#pragma unroll
    for (int k = 0; k < 4; k++) {
      const int idx = tid + k * 256;
      const int off = atomicAdd(&bins[loads[k]], 1);
      tbl[base[loads[k]] + off] = (uint32_t)(((idx >> 9) << 9) | (idx & 511));
    }
  }
}

// Flash attention, deterministic 2-way split per (h, q-tile) — R7/R11-
// verified structure. 1024 blocks x 512 thr, ALL co-resident (32KB LDS,
// 60 VGPR -> 4 blocks/CU). bid folds to load rank {u, 511-u, 512+u,
// 1023-u}. Halves store partials to OpA / OpB (plain f32, exactly once).
__global__ __launch_bounds__(512) void attn_kernel(const bf16* __restrict__ Q,
                                                   const bf16* __restrict__ Kb,
                                                   const bf16* __restrict__ Vtb,
                                                   float* __restrict__ OpA,
                                                   float* __restrict__ OpB,
                                                   float* __restrict__ lpart,
                                                   const uint32_t* __restrict__ tbl) {
  __shared__ __align__(16) bf16 Ks[2][64 * 64];  // [buf][key][d] swizzled
  __shared__ __align__(16) bf16 Vt[2][64 * 64];  // [buf][d][key] swizzled

  const int u = blockIdx.x & 255, sfold = blockIdx.x >> 8;
  const int r = (sfold == 0) ? u : (sfold == 1) ? (511 - u)
                : (sfold == 2) ? (512 + u) : (1023 - u);
  const uint32_t e = tbl[r];
  const int p = e & 511, hf = (int)(e >> 9);
  const int h = p & 31, t = p >> 5;

  const float slope2 = exp2f(-0.25f * (float)(h + 1)) * 1.44269504f;
  const int lo_key = t * 128 - (int)(WTHR / slope2);
  const int lo_t = (lo_key <= 0) ? 0 : (lo_key >> 6);
  const int m = 2 * t + 2 - lo_t;        // >= 2
  const int c0 = (m + 1) >> 1;
  const int kbeg = hf ? (lo_t + c0) : lo_t;
  const int cnt = hf ? (m >> 1) : c0;    // >= 1 always

  const int tid = threadIdx.x;
  const int wave = tid >> 6;  // 0..7 -> q-rows wave*16..+15
  const int lane = tid & 63;
  const int quad = lane >> 4, l16 = lane & 15;
  const float scale2 = 0.125f * 1.44269504f;
  const bf16x4 ones = {(bf16)1.f, (bf16)1.f, (bf16)1.f, (bf16)1.f};

  float cq[4];
#pragma unroll
  for (int rr = 0; rr < 4; rr++) cq[rr] = slope2 * (float)(quad * 4 + rr);
  const float s16 = slope2 * 16.f;

  const int qi = t * 128 + wave * 16 + l16;
  const int qw0 = t * 128 + wave * 16;
  bf16x8 qf[2];
#pragma unroll
  for (int kk = 0; kk < 2; kk++)
    qf[kk] = *(const bf16x8*)(&Q[(size_t)qi * 2048 + h * 64 + kk * 32 + quad * 8]);

  floatx4 oacc[4];
#pragma unroll
  for (int dt = 0; dt < 4; dt++) oacc[dt] = (floatx4)0.f;
  floatx4 lacc = (floatx4)0.f;

  // staging: 512 threads stage 64x64 K and V tiles (one bf16x8 each)
  const int r0 = tid >> 3, sl = tid & 7;     // row 0..63, 16B slot 0..7
  const int wsw = ((sl ^ (r0 & 7)) << 3);    // XOR-swizzled elem offset
  const int sx = l16 & 7;                    // read-side swizzle bits

  const int kn = kbeg * 64;
  bf16x8 kreg = *(const bf16x8*)(&Kb[(size_t)(kn + r0) * 64 + sl * 8]);
  bf16x8 vreg = *(const bf16x8*)(&Vtb[(size_t)r0 * 2048 + kn + sl * 8]);

  for (int i = 0; i < cnt; i++) {
    const int kt = kbeg + i;
    const int buf = i & 1;
    *(bf16x8*)(&Ks[buf][r0 * 64 + wsw]) = kreg;
    *(bf16x8*)(&Vt[buf][r0 * 64 + wsw]) = vreg;
    __syncthreads();  // tile kt visible
    if (i + 1 < cnt) {  // prefetch next tile (kt+1 <= 31 by construction)
      const int kn2 = (kt + 1) * 64;
      kreg = *(const bf16x8*)(&Kb[(size_t)(kn2 + r0) * 64 + sl * 8]);
      vreg = *(const bf16x8*)(&Vtb[(size_t)r0 * 2048 + kn2 + sl * 8]);
    }
    const int k0 = kt * 64;
    if (k0 > qw0 + 15) continue;                               // causal skip
    if ((float)(qw0 - k0 - 63) * slope2 > WTHR) continue;      // ALiBi window

    const bf16* ks = Ks[buf];
    const bf16* vs = Vt[buf];

    // S^T[key][q] = K . Q^T
    floatx4 s[4];
#pragma unroll
    for (int mt = 0; mt < 4; mt++) s[mt] = (floatx4)0.f;
#pragma unroll
    for (int kk = 0; kk < 2; kk++) {
#pragma unroll
      for (int mt = 0; mt < 4; mt++) {
        bf16x8 kf = *(const bf16x8*)(
            &ks[(mt * 16 + l16) * 64 + (((kk * 4 + quad) ^ sx) << 3)]);
        s[mt] = MFMA32(kf, qf[kk], s[mt]);
      }
    }

    // p = exp2(s*scale2 + slope2*(j-i)); scores bounded -> no running max
    const float base0 = slope2 * (float)(k0 - qi);
    bf16x4 pb[4];
    if (k0 + 63 <= qw0) {  // interior for the whole wave: no mask
      float b = base0;
#pragma unroll
      for (int mt = 0; mt < 4; mt++) {
        bf16x4 tb;
#pragma unroll
        for (int rr = 0; rr < 4; rr++)
          tb[rr] = (bf16)exp2f(__builtin_fmaf(s[mt][rr], scale2, b + cq[rr]));
        pb[mt] = tb;
        b += s16;
      }
    } else {  // diagonal tile: per-lane causal mask
      const int qloc = qi - k0;
      float b = base0;
#pragma unroll
      for (int mt = 0; mt < 4; mt++) {
        bf16x4 tb;
#pragma unroll
        for (int rr = 0; rr < 4; rr++) {
          const int moff = mt * 16 + quad * 4 + rr;
          const float pv = exp2f(__builtin_fmaf(s[mt][rr], scale2, b + cq[rr]));
          tb[rr] = (moff <= qloc) ? (bf16)pv : (bf16)0.f;
        }
        pb[mt] = tb;
        b += s16;
      }
    }

    // O^T[d][q] += V^T . P^T ; l += 1 . P^T (matrix-pipe row-sum)
#pragma unroll
    for (int mt = 0; mt < 4; mt++) {
      lacc = mfma16(ones, pb[mt], lacc);
#pragma unroll
      for (int dt = 0; dt < 4; dt++) {
        const int slot = 2 * mt + (quad >> 1);
        const bf16x4 va = *(const bf16x4*)(
            &vs[(dt * 16 + l16) * 64 + ((slot ^ sx) << 3) + (quad & 1) * 4]);
        oacc[dt] = mfma16(va, pb[mt], oacc[dt]);
      }
    }
  }

  // flush partial (plain f32 stores; each slot written exactly once)
  float* op = (hf ? OpB : OpA) + (size_t)qi * 2048 + h * 64;
#pragma unroll
  for (int dt = 0; dt < 4; dt++)
#pragma unroll
    for (int rr = 0; rr < 4; rr++)
      op[dt * 16 + quad * 4 + rr] = oacc[dt][rr];
  if (quad == 0) lpart[(size_t)hf * 65536 + (size_t)qi * 32 + h] = lacc[0];
}

// AO[qi][e] = (P0+P1)[qi][e] / (l0+l1)[qi][e>>6], bf16. 2048 blocks x 256.
__global__ __launch_bounds__(256) void norm_o(const float* __restrict__ P0,
                                              const float* __restrict__ P1,
                                              const float* __restrict__ L,
                                              bf16* __restrict__ AO) {
  const int idx = blockIdx.x * 256 + threadIdx.x;
  const int qi = idx >> 8;
  const int cs = (idx & 255) << 3;
  const int h = cs >> 6;
  const float l = L[(size_t)qi * 32 + h] + L[65536 + (size_t)qi * 32 + h];
  const float linv = 1.f / l;
  const float4 a0 = *(const float4*)(P0 + (size_t)qi * 2048 + cs);
  const float4 a1 = *(const float4*)(P0 + (size_t)qi * 2048 + cs + 4);
  const float4 b0 = *(const float4*)(P1 + (size_t)qi * 2048 + cs);
  const float4 b1 = *(const float4*)(P1 + (size_t)qi * 2048 + cs + 4);
  bf16x8 o;
  o[0] = (bf16)((a0.x + b0.x) * linv); o[1] = (bf16)((a0.y + b0.y) * linv);
  o[2] = (bf16)((a0.z + b0.z) * linv); o[3] = (bf16)((a0.w + b0.w) * linv);
  o[4] = (bf16)((a1.x + b1.x) * linv); o[5] = (bf16)((a1.y + b1.y) * linv);
  o[6] = (bf16)((a1.z + b1.z) * linv); o[7] = (bf16)((a1.w + b1.w) * linv);
  *(bf16x8*)(AO + (size_t)qi * 2048 + cs) = o;
}

extern "C" void kernel_launch(void* const* d_in, const int* in_sizes, int n_in,
                              void* d_out, int out_size, void* d_ws,
                              size_t ws_size, hipStream_t stream) {
  (void)in_sizes; (void)n_in; (void)out_size; (void)ws_size;
  const float* x = (const float*)d_in[0];
  const float* Wq = (const float*)d_in[1];
  const float* Wk = (const float*)d_in[2];
  const float* Wv = (const float*)d_in[3];
  const float* Wo = (const float*)d_in[4];
  float* out = (float*)d_out;

  const size_t NE = (size_t)2048 * 2048;
  bf16* xb = (bf16*)d_ws;              // 8 MB (reused as OpA lo half)
  bf16* Wqb = xb + NE;                 // 8 MB (reused as OpA hi half)
  bf16* Wob = Wqb + NE;                // 8 MB
  bf16* Qb = Wob + NE;                 // 8 MB (reused as AO after attn)
  float* Kf = (float*)(Qb + NE);       // 512 KB (reused as lpart, both halves)
  float* Vf = Kf + 2048 * 64;          // 512 KB (reused as schedule table)
  bf16* Kb = (bf16*)(Vf + 2048 * 64);  // 256 KB
  bf16* Vtb = Kb + 2048 * 64;          // 256 KB  (end of ws usage: ~33.5 MB)
  float* OpA = (float*)d_ws;           // 16 MB f32, over xb+Wqb (dead by attn)
  float* OpB = out;                    // 16 MB f32 scratch (out written last)
  float* lpart = Kf;                   // 512 KB f32 (l0 + l1), over Kf
  uint32_t* tbl = (uint32_t*)Vf;       // 4 KB, over Vf (dead after pack_mk)
  bf16* AO = Qb;                       // normalize output (Q dead after attn)

  prep<<<4352, 256, 0, stream>>>(x, xb, Wq, Wqb, Kf);
  qkv_gemm<<<2688, 256, 0, stream>>>(xb, Wqb, Qb, Wk, Wv, Kf, Vf, Wo, Wob);
  pack_mk<<<513, 256, 0, stream>>>(Kf, Vf, Kb, Vtb, tbl);
  attn_kernel<<<1024, 512, 0, stream>>>(Qb, Kb, Vtb, OpA, OpB, lpart, tbl);
  norm_o<<<2048, 256, 0, stream>>>(OpA, OpB, lpart, AO);
  gemm_bt_a<float><<<dim3(16, 32), 256, 0, stream>>>(AO, Wob, out, 2048, 2048, 2048);
}